// Round 11
// baseline (4849.704 us; speedup 1.0000x reference)
//
#include <hip/hip_runtime.h>

#define F_IN 512
#define F_OUT 256
#define BM 128
#define BN 256
#define BK 64

#define RB_BITS 6            // 64 rows per bucket
#define RPB 64
#define NBUCK 2048           // allocated buckets (used: ceil(n_nodes/64) = 1563)
#define NSUB 8               // sub-buckets (one per XCD via blockIdx&7)
#define CAP_SUB 512          // int2 slots per sub-segment (mean 256, +17 sigma)
#define SLOTS_PER_BUCKET (NSUB * CAP_SUB)   // 4096
#define LDSCAP 3072          // max raw edges per bucket in sort LDS (mean 2048, +22 sigma)
#define CSTR 16              // ints between cursors (own 64B line each)
#define NBIN2 3328           // col-sort bins (col>>5; max 3124) = 256*13
#define BPT 13               // bins per thread in scan

typedef __attribute__((ext_vector_type(8))) short bf16x8;
typedef __attribute__((ext_vector_type(4))) float f32x4;
typedef __attribute__((ext_vector_type(4))) int i32x4;

__device__ __forceinline__ ushort f2bf(float f) {
    union { float f; unsigned u; } c{f};
    unsigned r = (c.u + 0x7FFF + ((c.u >> 16) & 1)) >> 16;  // RNE
    return (ushort)r;
}
__device__ __forceinline__ float bf2f(ushort b) {
    union { unsigned u; float f; } c{(unsigned)b << 16};
    return c.f;
}

// ---------------------------------------------------------------------------
// W [512,256] fp32  ->  Wt [256,512] bf16 (transposed). 131072 elems.
// ---------------------------------------------------------------------------
__global__ __launch_bounds__(256) void conv_w(const float* __restrict__ w,
                                              ushort* __restrict__ wt) {
    int idx = blockIdx.x * 256 + threadIdx.x;
    int k = idx & (F_IN - 1);
    int n = idx >> 9;
    wt[(size_t)n * F_IN + k] = f2bf(w[(size_t)k * F_OUT + n]);
}

// ---------------------------------------------------------------------------
// FUSED: gemm blocks + bucket_place blocks interleaved 1:2 by blockIdx%3.
// gemm is MFMA/VALU-bound, place is fabric-latency-bound — complementary
// pipes co-resident per CU overlap (m114), hiding place's time.
// ---------------------------------------------------------------------------
__global__ __launch_bounds__(512) void gemm_place(const float* __restrict__ x,
                                                  const ushort* __restrict__ wt,
                                                  ushort* __restrict__ h,
                                                  int n_nodes,
                                                  const int* __restrict__ rows,
                                                  const int* __restrict__ cols,
                                                  const float* __restrict__ vals,
                                                  int* __restrict__ bcur,
                                                  int2* __restrict__ edges,
                                                  int n_edges,
                                                  int ngemm) {
    __shared__ short As[BM * BK];   // 16 KB
    __shared__ short Bs[BN * BK];   // 32 KB
    const int bid = blockIdx.x;
    const int t = threadIdx.x;

    const bool is_gemm = (bid % 3 == 0) && (bid / 3 < ngemm);
    if (!is_gemm) {
        // ---------------- bucket_place path ----------------
        const int place_id = (bid < 3 * ngemm) ? (bid - bid / 3 - 1) : (bid - ngemm);
        const int sub = bid & (NSUB - 1);
        int base = (place_id * 512 + t) * 4;
        if (base >= n_edges) return;
        if (base + 3 < n_edges) {
            i32x4 r4 = __builtin_nontemporal_load(reinterpret_cast<const i32x4*>(rows + base));
            i32x4 c4 = __builtin_nontemporal_load(reinterpret_cast<const i32x4*>(cols + base));
            f32x4 v4 = __builtin_nontemporal_load(reinterpret_cast<const f32x4*>(vals + base));
#pragma unroll
            for (int j = 0; j < 4; ++j) {
                int r = r4[j];
                int bs = (r >> RB_BITS) * NSUB + sub;
                int p = atomicAdd(&bcur[bs * CSTR], 1);
                if (p < CAP_SUB)
                    edges[(size_t)bs * CAP_SUB + p] =
                        make_int2(((r & (RPB - 1)) << 17) | c4[j], __float_as_int(v4[j]));
            }
        } else {
            for (int j = 0; j < 4 && base + j < n_edges; ++j) {
                int r = rows[base + j];
                int bs = (r >> RB_BITS) * NSUB + sub;
                int p = atomicAdd(&bcur[bs * CSTR], 1);
                if (p < CAP_SUB)
                    edges[(size_t)bs * CAP_SUB + p] =
                        make_int2(((r & (RPB - 1)) << 17) | cols[base + j],
                                  __float_as_int(vals[base + j]));
            }
        }
        return;
    }

    // ---------------- gemm path ----------------
    const int gb = bid / 3;
    const int lane = t & 63;
    const int w = t >> 6;           // 0..7
    const int wm = w >> 2;          // 0..1
    const int wn = w & 3;           // 0..3
    const int row0 = gb * BM;

    f32x4 acc[4][4] = {};

    const int arow = t >> 2;                 // 0..127
    const int akq  = (t & 3) << 4;           // 0,16,32,48
    const bool avalid = (row0 + arow) < n_nodes;
    const float* xsrc = x + (size_t)(row0 + arow) * F_IN + akq;

    const int lrow = lane & 15;
    const int koff = (lane >> 4) << 3;       // 0,8,16,24

    f32x4 fA[4];
    bf16x8 fB[4];

    {
        if (avalid) {
            const f32x4* s4 = reinterpret_cast<const f32x4*>(xsrc);
            fA[0] = __builtin_nontemporal_load(s4 + 0);
            fA[1] = __builtin_nontemporal_load(s4 + 1);
            fA[2] = __builtin_nontemporal_load(s4 + 2);
            fA[3] = __builtin_nontemporal_load(s4 + 3);
        } else {
            fA[0] = 0.f; fA[1] = 0.f; fA[2] = 0.f; fA[3] = 0.f;
        }
#pragma unroll
        for (int p = 0; p < 4; ++p) {
            int cid = p * 512 + t;
            int n = cid >> 3;
            int j = cid & 7;
            fB[p] = *reinterpret_cast<const bf16x8*>(wt + (size_t)n * F_IN + j * 8);
        }
    }

    for (int k0 = 0; k0 < F_IN; k0 += BK) {
#pragma unroll
        for (int q = 0; q < 2; ++q) {
            bf16x8 v;
#pragma unroll
            for (int j = 0; j < 8; ++j) v[j] = (short)f2bf(fA[q * 2 + (j >> 2)][j & 3]);
            int kk = akq + q * 8;
            int idx = arow * BK + (kk ^ ((arow & 7) << 3));
            *reinterpret_cast<bf16x8*>(&As[idx]) = v;
        }
#pragma unroll
        for (int p = 0; p < 4; ++p) {
            int cid = p * 512 + t;
            int n = cid >> 3;
            int j = cid & 7;
            int idx = n * BK + ((j * 8) ^ ((n & 7) << 3));
            *reinterpret_cast<bf16x8*>(&Bs[idx]) = fB[p];
        }
        __syncthreads();

        if (k0 + BK < F_IN) {
            if (avalid) {
                const f32x4* s4 = reinterpret_cast<const f32x4*>(xsrc + k0 + BK);
                fA[0] = __builtin_nontemporal_load(s4 + 0);
                fA[1] = __builtin_nontemporal_load(s4 + 1);
                fA[2] = __builtin_nontemporal_load(s4 + 2);
                fA[3] = __builtin_nontemporal_load(s4 + 3);
            }
#pragma unroll
            for (int p = 0; p < 4; ++p) {
                int cid = p * 512 + t;
                int n = cid >> 3;
                int j = cid & 7;
                fB[p] = *reinterpret_cast<const bf16x8*>(wt + (size_t)n * F_IN + k0 + BK + j * 8);
            }
        }

#pragma unroll
        for (int kk = 0; kk < BK; kk += 32) {
            bf16x8 a[4], b[4];
#pragma unroll
            for (int m = 0; m < 4; ++m) {
                int r = wm * 64 + m * 16 + lrow;
                int idx = r * BK + ((kk + koff) ^ ((r & 7) << 3));
                a[m] = *reinterpret_cast<const bf16x8*>(&As[idx]);
            }
#pragma unroll
            for (int n = 0; n < 4; ++n) {
                int r = wn * 64 + n * 16 + lrow;
                int idx = r * BK + ((kk + koff) ^ ((r & 7) << 3));
                b[n] = *reinterpret_cast<const bf16x8*>(&Bs[idx]);
            }
#pragma unroll
            for (int m = 0; m < 4; ++m)
#pragma unroll
                for (int n = 0; n < 4; ++n)
                    acc[m][n] = __builtin_amdgcn_mfma_f32_16x16x32_bf16(a[m], b[n], acc[m][n], 0, 0, 0);
        }
        __syncthreads();
    }

    const int rbase = (lane >> 4) << 2;
#pragma unroll
    for (int m = 0; m < 4; ++m) {
#pragma unroll
        for (int r = 0; r < 4; ++r) {
            int orow = row0 + wm * 64 + m * 16 + rbase + r;
            if (orow < n_nodes) {
                ushort* dst = h + (size_t)orow * F_OUT + wn * 64 + lrow;
#pragma unroll
                for (int n = 0; n < 4; ++n) dst[n * 16] = f2bf(acc[m][n][r]);
            }
        }
    }
}

// ---------------------------------------------------------------------------
// Pass 2: one block per 64-row bucket. Concatenate the 8 sub-lists into LDS,
// 3328-bin COLUMN histogram (bin = col>>5), exclusive scan, counting-sort
// scatter -> bucket's edges compacted and globally col-ordered (kept packed:
// {row6<<17|col, val}). bcnt[b] = edge count. All raw data is in LDS before
// any global write.
// ---------------------------------------------------------------------------
__global__ __launch_bounds__(256) void bucket_sort(const int* __restrict__ bcur,
                                                   int2* __restrict__ edges,
                                                   int* __restrict__ bcnt,
                                                   int n_nodes) {
    __shared__ int2 raw[LDSCAP];          // 24 KB
    __shared__ int cnt[NBIN2];            // 13 KB
    __shared__ int wsum[4];
    __shared__ int wbase[4];
    const int b = blockIdx.x;
    const int t = threadIdx.x;
    const size_t bbase = (size_t)b * SLOTS_PER_BUCKET;

    for (int i = t; i < NBIN2; i += 256) cnt[i] = 0;
    __syncthreads();

    // concatenate sub-lists into LDS + column histogram
    int nraw = 0;
#pragma unroll
    for (int s = 0; s < NSUB; ++s) {
        int ns = bcur[(b * NSUB + s) * CSTR];
        if (ns > CAP_SUB) ns = CAP_SUB;
        int take = ns;
        if (nraw + take > LDSCAP) take = LDSCAP - nraw;
        for (int i = t; i < take; i += 256) {
            int2 e = edges[bbase + (size_t)s * CAP_SUB + i];
            raw[nraw + i] = e;
            atomicAdd(&cnt[(e.x & 0x1FFFF) >> 5], 1);
        }
        nraw += take;
    }
    __syncthreads();

    // exclusive scan over 3328 bins (13 per thread)
    int s_t = 0;
#pragma unroll
    for (int j = 0; j < BPT; ++j) s_t += cnt[t * BPT + j];
    int x = s_t;
#pragma unroll
    for (int d = 1; d < 64; d <<= 1) {
        int y = __shfl_up(x, d, 64);
        if ((t & 63) >= d) x += y;
    }
    if ((t & 63) == 63) wsum[t >> 6] = x;
    __syncthreads();
    if (t == 0) {
        int r = 0;
#pragma unroll
        for (int q = 0; q < 4; ++q) { wbase[q] = r; r += wsum[q]; }
    }
    __syncthreads();
    int run = wbase[t >> 6] + (x - s_t);
#pragma unroll
    for (int j = 0; j < BPT; ++j) {
        int c = cnt[t * BPT + j];
        cnt[t * BPT + j] = run;
        run += c;
    }
    __syncthreads();

    // counting-sort scatter (global col order within bucket), keep packed
    for (int i = t; i < nraw; i += 256) {
        int2 e = raw[i];
        int pos = atomicAdd(&cnt[(e.x & 0x1FFFF) >> 5], 1);
        edges[bbase + pos] = e;
    }
    if (t == 0) bcnt[b] = nraw;
}

// ---------------------------------------------------------------------------
// Column-major SpMM + ReLU. Block = one 64-row bucket, 512 thr (8 waves),
// 64 KB LDS fp32 accumulator olds[64][256] (feat-permuted: feat f lives at
// dword row*256 + (f&3)*64 + (f>>2) -> ds_add banks are 2-way = free).
// Waves walk the col-sorted edge list interleaved (stride 8): the whole
// block — and, since all buckets progress at matched rates, the whole
// machine — gathers h inside a narrow moving column window -> L2/L3 hits.
// Per edge: 8B broadcast edge load, 512B coalesced h-row gather (ushort4 per
// lane), 4 conflict-free LDS float atomics. 2-deep pipeline (pairs i, i+8).
// ---------------------------------------------------------------------------
__global__ __launch_bounds__(512) void spmm_lds(const int* __restrict__ bcnt,
                                                const int2* __restrict__ edges,
                                                const ushort* __restrict__ h,
                                                float* __restrict__ out,
                                                int n_nodes) {
    __shared__ float olds[RPB * F_OUT];   // 65536 B
    const int b = blockIdx.x;
    const int t = threadIdx.x;
    const int wv = t >> 6;
    const int lane = t & 63;
    const size_t bbase = (size_t)b * SLOTS_PER_BUCKET;

    f32x4* oz = reinterpret_cast<f32x4*>(olds);
#pragma unroll
    for (int j = 0; j < 8; ++j) oz[j * 512 + t] = 0.f;   // 4096 float4
    __syncthreads();

    const int n = bcnt[b];
    for (int i = wv; i < n; i += 16) {
        int2 e0 = edges[bbase + i];
        int i1 = i + 8;
        int2 e1 = (i1 < n) ? edges[bbase + i1] : make_int2(0, 0);
        ushort4 g0 = *reinterpret_cast<const ushort4*>(
            h + (size_t)(e0.x & 0x1FFFF) * F_OUT + lane * 4);
        ushort4 g1 = *reinterpret_cast<const ushort4*>(
            h + (size_t)(e1.x & 0x1FFFF) * F_OUT + lane * 4);
        float v0 = __int_as_float(e0.y);
        float v1 = __int_as_float(e1.y);
        int r0 = (e0.x >> 17) * F_OUT;
        int r1 = (e1.x >> 17) * F_OUT;
        atomicAdd(&olds[r0 + lane],       v0 * bf2f(g0.x));
        atomicAdd(&olds[r0 + 64 + lane],  v0 * bf2f(g0.y));
        atomicAdd(&olds[r0 + 128 + lane], v0 * bf2f(g0.z));
        atomicAdd(&olds[r0 + 192 + lane], v0 * bf2f(g0.w));
        atomicAdd(&olds[r1 + lane],       v1 * bf2f(g1.x));
        atomicAdd(&olds[r1 + 64 + lane],  v1 * bf2f(g1.y));
        atomicAdd(&olds[r1 + 128 + lane], v1 * bf2f(g1.z));
        atomicAdd(&olds[r1 + 192 + lane], v1 * bf2f(g1.w));
    }
    __syncthreads();

    // epilogue: un-permute, ReLU, NT store. thread q -> row q>>6, fq = q&63,
    // feats {4fq, 4fq+1, 4fq+2, 4fq+3} from perm slots {fq, 64+fq, 128+fq, 192+fq}.
    const int row0 = b * RPB;
    for (int q = t; q < RPB * 64; q += 512) {
        int row = q >> 6;
        int fq = q & 63;
        int gr = row0 + row;
        if (gr < n_nodes) {
            f32x4 o;
            o[0] = fmaxf(olds[row * F_OUT + fq], 0.f);
            o[1] = fmaxf(olds[row * F_OUT + 64 + fq], 0.f);
            o[2] = fmaxf(olds[row * F_OUT + 128 + fq], 0.f);
            o[3] = fmaxf(olds[row * F_OUT + 192 + fq], 0.f);
            __builtin_nontemporal_store(
                o, reinterpret_cast<f32x4*>(out + (size_t)gr * F_OUT + fq * 4));
        }
    }
}

static inline size_t align_up(size_t v, size_t a) { return (v + a - 1) & ~(a - 1); }

extern "C" void kernel_launch(void* const* d_in, const int* in_sizes, int n_in,
                              void* d_out, int out_size, void* d_ws, size_t ws_size,
                              hipStream_t stream) {
    const float* x    = (const float*)d_in[0];
    const int*   rows = (const int*)d_in[1];
    const int*   cols = (const int*)d_in[2];
    const float* vals = (const float*)d_in[3];
    const float* w    = (const float*)d_in[4];
    float* out = (float*)d_out;

    const int n_nodes = in_sizes[0] / F_IN;
    const int n_edges = in_sizes[1];
    const int nbuck_used = (n_nodes + RPB - 1) >> RB_BITS;   // 1563

    // ---- workspace layout (~120 MB) ----
    char* ws = (char*)d_ws;
    size_t off = 0;
    ushort* h   = (ushort*)(ws + off); off = align_up(off + (size_t)n_nodes * F_OUT * 2, 256);
    ushort* wt  = (ushort*)(ws + off); off = align_up(off + (size_t)F_OUT * F_IN * 2, 256);
    int2* edges = (int2*)(ws + off);   off = align_up(off + (size_t)NBUCK * SLOTS_PER_BUCKET * 8, 256);
    int* bcnt   = (int*)(ws + off);    off = align_up(off + (size_t)NBUCK * 4, 256);
    int* bcur   = (int*)(ws + off);    off = align_up(off + (size_t)NBUCK * NSUB * CSTR * 4, 256);
    (void)ws_size;

    // 1) Wt = bf16(W^T); zero cursors
    conv_w<<<(F_IN * F_OUT) / 256, 256, 0, stream>>>(w, wt);
    hipMemsetAsync(bcur, 0, (size_t)NBUCK * NSUB * CSTR * 4, stream);

    // 2) FUSED: h = bf16(x @ W) (MFMA) + bucket_place, interleaved 1:2
    const int ngemm  = (n_nodes + BM - 1) / BM;
    const int nplace = (n_edges + 2047) / 2048;
    gemm_place<<<ngemm + nplace, 512, 0, stream>>>(x, wt, h, n_nodes,
                                                   rows, cols, vals, bcur, edges,
                                                   n_edges, ngemm);

    // 3) per-bucket column counting sort
    bucket_sort<<<nbuck_used, 256, 0, stream>>>(bcur, edges, bcnt, n_nodes);

    // 4) column-major SpMM + ReLU (LDS accumulators, moving col window)
    spmm_lds<<<nbuck_used, 512, 0, stream>>>(bcnt, edges, h, out, n_nodes);
}

// Round 13
// 433.972 us; speedup vs baseline: 11.1752x; 11.1752x over previous
//
#include <hip/hip_runtime.h>

#define F_IN 512
#define F_OUT 256
#define BM 128
#define BN 256
#define BK 64

#define RB_BITS 6            // 64 rows per bucket
#define RPB 64
#define NBUCK 2048           // allocated buckets (used: ceil(n_nodes/64) = 1563)
#define NSUB 8               // sub-buckets (one per XCD via blockIdx&7)
#define CAP_SUB 512          // int2 slots per sub-segment (mean 256, +17 sigma)
#define SLOTS_PER_BUCKET (NSUB * CAP_SUB)   // 4096
#define LDSSORT 3072         // sorted+padded int2 slots in LDS (mean ~2270, +18 sigma)
#define CSTR 16              // ints between cursors (own 64B line each)

typedef __attribute__((ext_vector_type(8))) short bf16x8;
typedef __attribute__((ext_vector_type(4))) float f32x4;
typedef __attribute__((ext_vector_type(4))) int i32x4;
typedef __attribute__((ext_vector_type(2))) int i32x2;

__device__ __forceinline__ ushort f2bf(float f) {
    union { float f; unsigned u; } c{f};
    unsigned r = (c.u + 0x7FFF + ((c.u >> 16) & 1)) >> 16;  // RNE
    return (ushort)r;
}
__device__ __forceinline__ float bf2f(ushort b) {
    union { unsigned u; float f; } c{(unsigned)b << 16};
    return c.f;
}

// ---------------------------------------------------------------------------
// W [512,256] fp32  ->  Wt [256,512] bf16 (transposed). 131072 elems.
// ---------------------------------------------------------------------------
__global__ __launch_bounds__(256) void conv_w(const float* __restrict__ w,
                                              ushort* __restrict__ wt) {
    int idx = blockIdx.x * 256 + threadIdx.x;
    int k = idx & (F_IN - 1);
    int n = idx >> 9;
    wt[(size_t)n * F_IN + k] = f2bf(w[(size_t)k * F_OUT + n]);
}

// ---------------------------------------------------------------------------
// FUSED: gemm blocks + bucket_place blocks interleaved 1:2 by blockIdx%3.
// gemm is MFMA/VALU-bound, place is fabric-latency-bound — complementary
// pipes co-resident per CU overlap (m114), hiding place's time.
// ---------------------------------------------------------------------------
__global__ __launch_bounds__(512) void gemm_place(const float* __restrict__ x,
                                                  const ushort* __restrict__ wt,
                                                  ushort* __restrict__ h,
                                                  int n_nodes,
                                                  const int* __restrict__ rows,
                                                  const int* __restrict__ cols,
                                                  const float* __restrict__ vals,
                                                  int* __restrict__ bcur,
                                                  int2* __restrict__ edges,
                                                  int n_edges,
                                                  int ngemm) {
    __shared__ short As[BM * BK];   // 16 KB
    __shared__ short Bs[BN * BK];   // 32 KB
    const int bid = blockIdx.x;
    const int t = threadIdx.x;

    const bool is_gemm = (bid % 3 == 0) && (bid / 3 < ngemm);
    if (!is_gemm) {
        // ---------------- bucket_place path ----------------
        const int place_id = (bid < 3 * ngemm) ? (bid - bid / 3 - 1) : (bid - ngemm);
        const int sub = bid & (NSUB - 1);
        int base = (place_id * 512 + t) * 4;
        if (base >= n_edges) return;
        if (base + 3 < n_edges) {
            i32x4 r4 = __builtin_nontemporal_load(reinterpret_cast<const i32x4*>(rows + base));
            i32x4 c4 = __builtin_nontemporal_load(reinterpret_cast<const i32x4*>(cols + base));
            f32x4 v4 = __builtin_nontemporal_load(reinterpret_cast<const f32x4*>(vals + base));
#pragma unroll
            for (int j = 0; j < 4; ++j) {
                int r = r4[j];
                int bs = (r >> RB_BITS) * NSUB + sub;
                int p = atomicAdd(&bcur[bs * CSTR], 1);
                if (p < CAP_SUB)
                    edges[(size_t)bs * CAP_SUB + p] =
                        make_int2(((r & (RPB - 1)) << 17) | c4[j], __float_as_int(v4[j]));
            }
        } else {
            for (int j = 0; j < 4 && base + j < n_edges; ++j) {
                int r = rows[base + j];
                int bs = (r >> RB_BITS) * NSUB + sub;
                int p = atomicAdd(&bcur[bs * CSTR], 1);
                if (p < CAP_SUB)
                    edges[(size_t)bs * CAP_SUB + p] =
                        make_int2(((r & (RPB - 1)) << 17) | cols[base + j],
                                  __float_as_int(vals[base + j]));
            }
        }
        return;
    }

    // ---------------- gemm path ----------------
    const int gb = bid / 3;
    const int lane = t & 63;
    const int w = t >> 6;           // 0..7
    const int wm = w >> 2;          // 0..1
    const int wn = w & 3;           // 0..3
    const int row0 = gb * BM;

    f32x4 acc[4][4] = {};

    const int arow = t >> 2;                 // 0..127
    const int akq  = (t & 3) << 4;           // 0,16,32,48
    const bool avalid = (row0 + arow) < n_nodes;
    const float* xsrc = x + (size_t)(row0 + arow) * F_IN + akq;

    const int lrow = lane & 15;
    const int koff = (lane >> 4) << 3;       // 0,8,16,24

    f32x4 fA[4];
    bf16x8 fB[4];

    {
        if (avalid) {
            const f32x4* s4 = reinterpret_cast<const f32x4*>(xsrc);
            fA[0] = __builtin_nontemporal_load(s4 + 0);
            fA[1] = __builtin_nontemporal_load(s4 + 1);
            fA[2] = __builtin_nontemporal_load(s4 + 2);
            fA[3] = __builtin_nontemporal_load(s4 + 3);
        } else {
            fA[0] = 0.f; fA[1] = 0.f; fA[2] = 0.f; fA[3] = 0.f;
        }
#pragma unroll
        for (int p = 0; p < 4; ++p) {
            int cid = p * 512 + t;
            int n = cid >> 3;
            int j = cid & 7;
            fB[p] = *reinterpret_cast<const bf16x8*>(wt + (size_t)n * F_IN + j * 8);
        }
    }

    for (int k0 = 0; k0 < F_IN; k0 += BK) {
#pragma unroll
        for (int q = 0; q < 2; ++q) {
            bf16x8 v;
#pragma unroll
            for (int j = 0; j < 8; ++j) v[j] = (short)f2bf(fA[q * 2 + (j >> 2)][j & 3]);
            int kk = akq + q * 8;
            int idx = arow * BK + (kk ^ ((arow & 7) << 3));
            *reinterpret_cast<bf16x8*>(&As[idx]) = v;
        }
#pragma unroll
        for (int p = 0; p < 4; ++p) {
            int cid = p * 512 + t;
            int n = cid >> 3;
            int j = cid & 7;
            int idx = n * BK + ((j * 8) ^ ((n & 7) << 3));
            *reinterpret_cast<bf16x8*>(&Bs[idx]) = fB[p];
        }
        __syncthreads();

        if (k0 + BK < F_IN) {
            if (avalid) {
                const f32x4* s4 = reinterpret_cast<const f32x4*>(xsrc + k0 + BK);
                fA[0] = __builtin_nontemporal_load(s4 + 0);
                fA[1] = __builtin_nontemporal_load(s4 + 1);
                fA[2] = __builtin_nontemporal_load(s4 + 2);
                fA[3] = __builtin_nontemporal_load(s4 + 3);
            }
#pragma unroll
            for (int p = 0; p < 4; ++p) {
                int cid = p * 512 + t;
                int n = cid >> 3;
                int j = cid & 7;
                fB[p] = *reinterpret_cast<const bf16x8*>(wt + (size_t)n * F_IN + k0 + BK + j * 8);
            }
        }

#pragma unroll
        for (int kk = 0; kk < BK; kk += 32) {
            bf16x8 a[4], b[4];
#pragma unroll
            for (int m = 0; m < 4; ++m) {
                int r = wm * 64 + m * 16 + lrow;
                int idx = r * BK + ((kk + koff) ^ ((r & 7) << 3));
                a[m] = *reinterpret_cast<const bf16x8*>(&As[idx]);
            }
#pragma unroll
            for (int n = 0; n < 4; ++n) {
                int r = wn * 64 + n * 16 + lrow;
                int idx = r * BK + ((kk + koff) ^ ((r & 7) << 3));
                b[n] = *reinterpret_cast<const bf16x8*>(&Bs[idx]);
            }
#pragma unroll
            for (int m = 0; m < 4; ++m)
#pragma unroll
                for (int n = 0; n < 4; ++n)
                    acc[m][n] = __builtin_amdgcn_mfma_f32_16x16x32_bf16(a[m], b[n], acc[m][n], 0, 0, 0);
        }
        __syncthreads();
    }

    const int rbase_ = (lane >> 4) << 2;
#pragma unroll
    for (int m = 0; m < 4; ++m) {
#pragma unroll
        for (int r = 0; r < 4; ++r) {
            int orow = row0 + wm * 64 + m * 16 + rbase_ + r;
            if (orow < n_nodes) {
                ushort* dst = h + (size_t)orow * F_OUT + wn * 64 + lrow;
#pragma unroll
                for (int n = 0; n < 4; ++n) dst[n * 16] = f2bf(acc[m][n][r]);
            }
        }
    }
}

// ---------------------------------------------------------------------------
// FUSED sort + SpMM + ReLU. Block = one 64-row bucket, 256 thr = 4 waves.
// A) histogram sub-lists (global read #1, LDS int atomics — native & fast)
// B) 64-lane padded(x8) scan -> per-row base/cnt in LDS; zero pad slots
// C) re-read sub-lists (global read #2, L2-warm), scatter unpacked {col,val}
//    into sorted LDS buffer (24 KB) — sorted edges never touch global
// D) wave w processes rows w, w+4, ...: broadcast LDS edge batches,
//    2-deep pipelined 512B h-row gathers, FMA into regs, ReLU, NT store.
// ---------------------------------------------------------------------------
struct EB { i32x4 e0, e1, e2, e3; };
struct GB { ushort4 g0, g1, g2, g3, g4, g5, g6, g7; };

__device__ __forceinline__ void load_eb_lds(EB& e, const int2* __restrict__ sl, int i) {
    const i32x4* p = reinterpret_cast<const i32x4*>(sl + i);  // uniform -> broadcast
    e.e0 = p[0]; e.e1 = p[1]; e.e2 = p[2]; e.e3 = p[3];
}
__device__ __forceinline__ void issue_gb(GB& g, const EB& e, const ushort* __restrict__ hf) {
    g.g0 = *reinterpret_cast<const ushort4*>(hf + (size_t)e.e0[0] * F_OUT);
    g.g1 = *reinterpret_cast<const ushort4*>(hf + (size_t)e.e0[2] * F_OUT);
    g.g2 = *reinterpret_cast<const ushort4*>(hf + (size_t)e.e1[0] * F_OUT);
    g.g3 = *reinterpret_cast<const ushort4*>(hf + (size_t)e.e1[2] * F_OUT);
    g.g4 = *reinterpret_cast<const ushort4*>(hf + (size_t)e.e2[0] * F_OUT);
    g.g5 = *reinterpret_cast<const ushort4*>(hf + (size_t)e.e2[2] * F_OUT);
    g.g6 = *reinterpret_cast<const ushort4*>(hf + (size_t)e.e3[0] * F_OUT);
    g.g7 = *reinterpret_cast<const ushort4*>(hf + (size_t)e.e3[2] * F_OUT);
}
__device__ __forceinline__ void fma1(float* acc, float v, ushort4 g) {
    acc[0] = fmaf(v, bf2f(g.x), acc[0]);
    acc[1] = fmaf(v, bf2f(g.y), acc[1]);
    acc[2] = fmaf(v, bf2f(g.z), acc[2]);
    acc[3] = fmaf(v, bf2f(g.w), acc[3]);
}
__device__ __forceinline__ void fma_gb(float* acc, const EB& e, const GB& g) {
    fma1(acc, __int_as_float(e.e0[1]), g.g0);
    fma1(acc, __int_as_float(e.e0[3]), g.g1);
    fma1(acc, __int_as_float(e.e1[1]), g.g2);
    fma1(acc, __int_as_float(e.e1[3]), g.g3);
    fma1(acc, __int_as_float(e.e2[1]), g.g4);
    fma1(acc, __int_as_float(e.e2[3]), g.g5);
    fma1(acc, __int_as_float(e.e3[1]), g.g6);
    fma1(acc, __int_as_float(e.e3[3]), g.g7);
}

__global__ __launch_bounds__(256) void sort_spmm(const int* __restrict__ bcur,
                                                 const int2* __restrict__ edges,
                                                 const ushort* __restrict__ h,
                                                 float* __restrict__ out,
                                                 int n_nodes) {
    __shared__ int2 sorted[LDSSORT];   // 24 KB
    __shared__ int cnt[RPB];
    __shared__ int rbase[RPB];
    __shared__ int rcnt[RPB];
    __shared__ int lcur[RPB];
    const int b = blockIdx.x;
    const int t = threadIdx.x;
    const int wv = t >> 6;
    const int lane = t & 63;
    const size_t bbase = (size_t)b * SLOTS_PER_BUCKET;

    if (t < RPB) cnt[t] = 0;
    __syncthreads();

    // ---- A: histogram (global read #1) ----
#pragma unroll
    for (int s = 0; s < NSUB; ++s) {
        int ns = bcur[(b * NSUB + s) * CSTR];
        if (ns > CAP_SUB) ns = CAP_SUB;
        for (int i = t; i < ns; i += 256) {
            i32x2 ev = __builtin_nontemporal_load(
                reinterpret_cast<const i32x2*>(edges + bbase + (size_t)s * CAP_SUB + i));
            atomicAdd(&cnt[ev[0] >> 17], 1);
        }
    }
    __syncthreads();

    // ---- B: padded(x8) exclusive scan over 64 rows (wave 0), zero pads ----
    int c = (t < RPB) ? cnt[t] : 0;
    int padded = (c + 7) & ~7;
    int x = padded;
#pragma unroll
    for (int d = 1; d < 64; d <<= 1) {
        int y = __shfl_up(x, d, 64);
        if (lane >= d) x += y;
    }
    if (t < RPB) {
        int base = x - padded;                    // exclusive
        if (base > LDSSORT) base = LDSSORT;
        int end = base + padded;
        if (end > LDSSORT) end = LDSSORT;
        rbase[t] = base;
        rcnt[t] = (end - base) & ~7;
        lcur[t] = base;
        for (int j = c; j < padded; ++j) {
            int p = base + j;
            if (p < LDSSORT) sorted[p] = make_int2(0, 0);
        }
    }
    __syncthreads();

    // ---- C: scatter (global read #2, L2-warm) into sorted LDS ----
#pragma unroll
    for (int s = 0; s < NSUB; ++s) {
        int ns = bcur[(b * NSUB + s) * CSTR];
        if (ns > CAP_SUB) ns = CAP_SUB;
        for (int i = t; i < ns; i += 256) {
            i32x2 ev = __builtin_nontemporal_load(
                reinterpret_cast<const i32x2*>(edges + bbase + (size_t)s * CAP_SUB + i));
            int pos = atomicAdd(&lcur[ev[0] >> 17], 1);
            if (pos < LDSSORT) sorted[pos] = make_int2(ev[0] & 0x1FFFF, ev[1]);
        }
    }
    __syncthreads();

    // ---- D: per-wave row processing with 2-deep gather pipeline ----
    const int row0 = b * RPB;
    const ushort* hf = h + lane * 4;
    for (int row = wv; row < RPB; row += 4) {
        const int beg = rbase[row];
        const int nb = rcnt[row] >> 3;
        float acc[4] = {0.f, 0.f, 0.f, 0.f};

        if (nb > 0) {
            EB ea, eb_;
            GB ga, gb;
            load_eb_lds(ea, sorted, beg);
            issue_gb(ga, ea, hf);
            int bi = 1;
            for (; bi + 1 < nb; bi += 2) {
                load_eb_lds(eb_, sorted, beg + bi * 8);
                issue_gb(gb, eb_, hf);
                fma_gb(acc, ea, ga);
                load_eb_lds(ea, sorted, beg + (bi + 1) * 8);
                issue_gb(ga, ea, hf);
                fma_gb(acc, eb_, gb);
            }
            if (bi < nb) {
                load_eb_lds(eb_, sorted, beg + bi * 8);
                issue_gb(gb, eb_, hf);
                fma_gb(acc, ea, ga);
                fma_gb(acc, eb_, gb);
            } else {
                fma_gb(acc, ea, ga);
            }
        }

        int gr = row0 + row;
        if (gr < n_nodes) {
            f32x4 o;
            o[0] = fmaxf(acc[0], 0.f);
            o[1] = fmaxf(acc[1], 0.f);
            o[2] = fmaxf(acc[2], 0.f);
            o[3] = fmaxf(acc[3], 0.f);
            __builtin_nontemporal_store(
                o, reinterpret_cast<f32x4*>(out + (size_t)gr * F_OUT + lane * 4));
        }
    }
}

static inline size_t align_up(size_t v, size_t a) { return (v + a - 1) & ~(a - 1); }

extern "C" void kernel_launch(void* const* d_in, const int* in_sizes, int n_in,
                              void* d_out, int out_size, void* d_ws, size_t ws_size,
                              hipStream_t stream) {
    const float* x    = (const float*)d_in[0];
    const int*   rows = (const int*)d_in[1];
    const int*   cols = (const int*)d_in[2];
    const float* vals = (const float*)d_in[3];
    const float* w    = (const float*)d_in[4];
    float* out = (float*)d_out;

    const int n_nodes = in_sizes[0] / F_IN;
    const int n_edges = in_sizes[1];
    const int nbuck_used = (n_nodes + RPB - 1) >> RB_BITS;   // 1563

    // ---- workspace layout (~120 MB) ----
    char* ws = (char*)d_ws;
    size_t off = 0;
    ushort* h   = (ushort*)(ws + off); off = align_up(off + (size_t)n_nodes * F_OUT * 2, 256);
    ushort* wt  = (ushort*)(ws + off); off = align_up(off + (size_t)F_OUT * F_IN * 2, 256);
    int2* edges = (int2*)(ws + off);   off = align_up(off + (size_t)NBUCK * SLOTS_PER_BUCKET * 8, 256);
    int* bcur   = (int*)(ws + off);    off = align_up(off + (size_t)NBUCK * NSUB * CSTR * 4, 256);
    (void)ws_size;

    // 1) Wt = bf16(W^T); zero cursors
    conv_w<<<(F_IN * F_OUT) / 256, 256, 0, stream>>>(w, wt);
    hipMemsetAsync(bcur, 0, (size_t)NBUCK * NSUB * CSTR * 4, stream);

    // 2) FUSED: h = bf16(x @ W) (MFMA) + bucket_place, interleaved 1:2
    const int ngemm  = (n_nodes + BM - 1) / BM;
    const int nplace = (n_edges + 2047) / 2048;
    gemm_place<<<ngemm + nplace, 512, 0, stream>>>(x, wt, h, n_nodes,
                                                   rows, cols, vals, bcur, edges,
                                                   n_edges, ngemm);

    // 3) FUSED: per-bucket LDS sort + row-wave SpMM + ReLU
    sort_spmm<<<nbuck_used, 256, 0, stream>>>(bcur, edges, h, out, n_nodes);
}